// Round 2
// baseline (698.848 us; speedup 1.0000x reference)
//
#include <hip/hip_runtime.h>
#include <hip/hip_bf16.h>
#include <stdint.h>

typedef __hip_bfloat16 bf16;
typedef __attribute__((ext_vector_type(8))) short short8;
typedef __attribute__((ext_vector_type(4))) float f32x4;

#define NB 32768
#define NC 1024
#define NH 1024
#define NS 8
#define NDC 64

__device__ __forceinline__ void gload_lds16(const void* g, void* l) {
    __builtin_amdgcn_global_load_lds((const __attribute__((address_space(1))) void*)g,
                                     (__attribute__((address_space(3))) void*)l, 16, 0, 0);
}

__device__ __forceinline__ short f2bf(float x) {
    bf16 h = __float2bfloat16(x);
    short s;
    __builtin_memcpy(&s, &h, 2);
    return s;
}

// ---------------- fp32 -> bf16 bulk convert (8 elems/thread) ----------------
__global__ __launch_bounds__(256) void convert_kernel(
    const float* __restrict__ in, bf16* __restrict__ out)
{
    const size_t i = ((size_t)blockIdx.x * 256 + threadIdx.x) * 8;
    float4 a = *(const float4*)(in + i);
    float4 b = *(const float4*)(in + i + 4);
    short8 v;
    v[0] = f2bf(a.x); v[1] = f2bf(a.y); v[2] = f2bf(a.z); v[3] = f2bf(a.w);
    v[4] = f2bf(b.x); v[5] = f2bf(b.y); v[6] = f2bf(b.z); v[7] = f2bf(b.w);
    *(short8*)((short*)out + i) = v;
}

// ---------------- batched tiled transpose + downcast: out[c][r] = bf16(in[r][c]) ----------------
__global__ __launch_bounds__(256) void transpose_kernel(
    const float* __restrict__ in, bf16* __restrict__ out,
    int R, int Ccols, long long in_bs, long long out_bs)
{
    __shared__ float tile[32][33];
    const float* inb = in + (long long)blockIdx.z * in_bs;
    bf16* outb = out + (long long)blockIdx.z * out_bs;
    int c0 = blockIdx.x * 32, r0 = blockIdx.y * 32;
    int tx = threadIdx.x, ty = threadIdx.y; // 32 x 8
#pragma unroll
    for (int i = 0; i < 32; i += 8)
        tile[ty + i][tx] = inb[(size_t)(r0 + ty + i) * Ccols + c0 + tx];
    __syncthreads();
#pragma unroll
    for (int i = 0; i < 32; i += 8)
        outb[(size_t)(c0 + ty + i) * R + r0 + tx] = __float2bfloat16(tile[tx][ty + i]);
}

// ---------------- style_contrib[s][h] = ba1[h] + sum_k style_emb[s][k]*Wa1[C+k][h] ----------------
__global__ __launch_bounds__(64) void style_contrib_kernel(
    const float* __restrict__ style_emb, const float* __restrict__ Wa1,
    const float* __restrict__ ba1, float* __restrict__ out)
{
    int h = blockIdx.x * 64 + threadIdx.x; // grid 16
    float acc[NS];
    float b = ba1[h];
#pragma unroll
    for (int s = 0; s < NS; ++s) acc[s] = b;
    for (int k = 0; k < NH; ++k) {
        float w = Wa1[(size_t)(NC + k) * NH + h];
#pragma unroll
        for (int s = 0; s < NS; ++s)
            acc[s] += style_emb[s * NH + k] * w;
    }
#pragma unroll
    for (int s = 0; s < NS; ++s) out[s * NH + h] = acc[s];
}

// ---------------- m97-style bf16 GEMM: C = epilogue(A(MxK) @ BT(NxK)^T) ----------------
// MODE 0: bf16 out = relu(acc + style_contrib[style_idx[row]][col])     -> hidden
// MODE 1: f32  out = acc + resid[row][col] + bias[col]                  -> adjusted_logits
// MODE 2: bf16 out = relu(acc + bias[col])                              -> h_cal
template<int MODE>
__global__ __launch_bounds__(256, 2) void gemm_kernel(
    const bf16* __restrict__ A, const bf16* __restrict__ BT,
    bf16* __restrict__ Cb, float* __restrict__ Cf,
    int N, int K,
    const float* __restrict__ style_contrib, const int* __restrict__ style_idx,
    const float* __restrict__ resid, const float* __restrict__ bias)
{
    __shared__ short lA[128 * 32];
    __shared__ short lB[128 * 32];

    const int t = threadIdx.x;
    const int lane = t & 63;
    const int wave = t >> 6;
    const int wr = wave >> 1;
    const int wc = wave & 1;
    const int bm0 = blockIdx.y * 128;
    const int bn0 = blockIdx.x * 128;

    const int r0 = t >> 2;        // staging row
    const int c8 = (t & 3) * 8;   // staging k-chunk

    const int mrow = lane & 15;
    const int quad = lane >> 4;

    f32x4 acc[4][4];
#pragma unroll
    for (int i = 0; i < 4; ++i)
#pragma unroll
        for (int j = 0; j < 4; ++j) acc[i][j] = (f32x4){0.f, 0.f, 0.f, 0.f};

    const bf16* gA = A + (size_t)(bm0 + r0) * K + c8;
    const bf16* gB = BT + (size_t)(bn0 + r0) * K + c8;

    for (int k0 = 0; k0 < K; k0 += 32) {
        // stage 128x32 bf16 A-tile and B-tile; LDS dst byte = t*16 (+4096 for rows 64..127)
        gload_lds16(gA + k0, lA + t * 8);
        gload_lds16(gA + (size_t)64 * K + k0, lA + 2048 + t * 8);
        gload_lds16(gB + k0, lB + t * 8);
        gload_lds16(gB + (size_t)64 * K + k0, lB + 2048 + t * 8);
        __syncthreads();

        short8 af[4], bfr[4];
#pragma unroll
        for (int i = 0; i < 4; ++i)
            af[i] = *(const short8*)(lA + (wr * 64 + i * 16 + mrow) * 32 + quad * 8);
#pragma unroll
        for (int j = 0; j < 4; ++j)
            bfr[j] = *(const short8*)(lB + (wc * 64 + j * 16 + mrow) * 32 + quad * 8);
#pragma unroll
        for (int i = 0; i < 4; ++i)
#pragma unroll
            for (int j = 0; j < 4; ++j)
                acc[i][j] = __builtin_amdgcn_mfma_f32_16x16x32_bf16(af[i], bfr[j], acc[i][j], 0, 0, 0);
        __syncthreads();
    }

    // epilogue: C/D layout col = lane&15, row = quad*4 + reg
#pragma unroll
    for (int i = 0; i < 4; ++i) {
#pragma unroll
        for (int r = 0; r < 4; ++r) {
            const int grow = bm0 + wr * 64 + i * 16 + quad * 4 + r;
            const float* scrow = nullptr;
            const float* resrow = nullptr;
            if (MODE == 0) scrow = style_contrib + (size_t)style_idx[grow] * N;
            if (MODE == 1) resrow = resid + (size_t)grow * N;
#pragma unroll
            for (int j = 0; j < 4; ++j) {
                const int gcol = bn0 + wc * 64 + j * 16 + mrow;
                float v = acc[i][j][r];
                if (MODE == 0) {
                    v += scrow[gcol];
                    v = fmaxf(v, 0.f);
                    Cb[(size_t)grow * N + gcol] = __float2bfloat16(v);
                } else if (MODE == 1) {
                    v += resrow[gcol] + bias[gcol];
                    Cf[(size_t)grow * N + gcol] = v;
                } else {
                    v += bias[gcol];
                    v = fmaxf(v, 0.f);
                    Cb[(size_t)grow * N + gcol] = __float2bfloat16(v);
                }
            }
        }
    }
}

// ---------------- row softmax (1024 cols), f32 in -> bf16 out ----------------
__global__ __launch_bounds__(256) void softmax_kernel(
    const float* __restrict__ in, bf16* __restrict__ out)
{
    const size_t row = blockIdx.x;
    const float* x = in + row * NC;
    bf16* o = out + row * NC;
    const int t = threadIdx.x;
    __shared__ float red[8];

    float v[4];
    float m = -1e30f;
#pragma unroll
    for (int i = 0; i < 4; ++i) {
        v[i] = x[t + i * 256];
        m = fmaxf(m, v[i]);
    }
#pragma unroll
    for (int off = 1; off < 64; off <<= 1) m = fmaxf(m, __shfl_xor(m, off, 64));
    const int wv = t >> 6;
    if ((t & 63) == 0) red[wv] = m;
    __syncthreads();
    const float gm = fmaxf(fmaxf(red[0], red[1]), fmaxf(red[2], red[3]));

    float s = 0.f;
#pragma unroll
    for (int i = 0; i < 4; ++i) {
        v[i] = __expf(v[i] - gm);
        s += v[i];
    }
#pragma unroll
    for (int off = 1; off < 64; off <<= 1) s += __shfl_xor(s, off, 64);
    if ((t & 63) == 0) red[4 + wv] = s;
    __syncthreads();
    const float inv = 1.0f / (red[4] + red[5] + red[6] + red[7]);
#pragma unroll
    for (int i = 0; i < 4; ++i) o[t + i * 256] = __float2bfloat16(v[i] * inv);
}

// ---------------- confidence: select style, 64-dot, sigmoid ----------------
__global__ __launch_bounds__(256) void conf_kernel(
    const bf16* __restrict__ hcal, const int* __restrict__ style_idx,
    const float* __restrict__ Wc2, const float* __restrict__ bc2,
    float* __restrict__ out)
{
    const int t = threadIdx.x;
    const int lane = t & 63;
    const int b = blockIdx.x * 4 + (t >> 6);
    const int s = style_idx[b];
    float p = __bfloat162float(hcal[(size_t)b * (NS * NDC) + s * NDC + lane]) *
              Wc2[s * NDC + lane];
#pragma unroll
    for (int off = 1; off < 64; off <<= 1) p += __shfl_xor(p, off, 64);
    if (lane == 0) {
        float z = p + bc2[s];
        out[b] = 1.0f / (1.0f + __expf(-z));
    }
}

extern "C" void kernel_launch(void* const* d_in, const int* in_sizes, int n_in,
                              void* d_out, int out_size, void* d_ws, size_t ws_size,
                              hipStream_t stream) {
    const float* logits    = (const float*)d_in[0];
    const int*   style_idx = (const int*)d_in[1];
    const float* style_emb = (const float*)d_in[2];
    const float* Wa1       = (const float*)d_in[3];
    const float* ba1       = (const float*)d_in[4];
    const float* Wa2       = (const float*)d_in[5];
    const float* ba2       = (const float*)d_in[6];
    const float* Wc1       = (const float*)d_in[7];
    const float* bc1       = (const float*)d_in[8];
    const float* Wc2       = (const float*)d_in[9];
    const float* bc2       = (const float*)d_in[10];

    char* ws = (char*)d_ws;
    bf16* logits_b = (bf16*)ws;        ws += (size_t)NB * NC * 2;          // 64 MB
    bf16* hidden = (bf16*)ws;          ws += (size_t)NB * NH * 2;          // 64 MB (reused as probs)
    bf16* W1T = (bf16*)ws;             ws += (size_t)NC * NH * 2;          // 2 MB
    bf16* W2T = (bf16*)ws;             ws += (size_t)NH * NC * 2;          // 2 MB
    bf16* Wc1T = (bf16*)ws;            ws += (size_t)NS * NDC * NC * 2;    // 1 MB
    float* style_contrib = (float*)ws; ws += (size_t)NS * NH * 4;          // 32 KB
    // hcal aliases logits_b: logits_b is dead after gemm<0> (gemm<1> uses fp32 logits residual)
    bf16* hcal = logits_b;                                                 // 32 MB

    float* adjusted = (float*)d_out;
    float* conf_out = (float*)d_out + (size_t)NB * NC;

    // logits -> bf16
    convert_kernel<<<(NB * NC) / (256 * 8), 256, 0, stream>>>(logits, logits_b);

    dim3 tb(32, 8);
    // W1T[n][k] = Wa1[k][n] (first C rows of Wa1)
    transpose_kernel<<<dim3(32, 32, 1), tb, 0, stream>>>(Wa1, W1T, NC, NH, 0, 0);
    // W2T[n][k] = Wa2[k][n]
    transpose_kernel<<<dim3(32, 32, 1), tb, 0, stream>>>(Wa2, W2T, NH, NC, 0, 0);
    // Wc1T[s*64+d][c] = Wc1[s][c][d]  (batched 1024x64 -> 64x1024 per style)
    transpose_kernel<<<dim3(2, 32, NS), tb, 0, stream>>>(Wc1, Wc1T, NC, NDC,
                                                         (long long)NC * NDC, (long long)NDC * NC);
    style_contrib_kernel<<<16, 64, 0, stream>>>(style_emb, Wa1, ba1, style_contrib);

    // hidden = relu(logits @ Wa1[:C] + style_contrib[style])
    gemm_kernel<0><<<dim3(NH / 128, NB / 128), 256, 0, stream>>>(
        logits_b, W1T, hidden, nullptr, NH, NC, style_contrib, style_idx, nullptr, nullptr);
    // adjusted = logits + hidden @ Wa2 + ba2   (f32 out, f32 residual)
    gemm_kernel<1><<<dim3(NC / 128, NB / 128), 256, 0, stream>>>(
        hidden, W2T, nullptr, adjusted, NC, NH, nullptr, nullptr, logits, ba2);
    // probs = softmax(adjusted)  (reuse hidden buffer)
    softmax_kernel<<<NB, 256, 0, stream>>>(adjusted, hidden);
    // hcal = relu(probs @ Wc1 + bc1), all styles dense (N = S*DC = 512)
    gemm_kernel<2><<<dim3((NS * NDC) / 128, NB / 128), 256, 0, stream>>>(
        hidden, Wc1T, hcal, nullptr, NS * NDC, NC, nullptr, nullptr, nullptr, bc1);
    // conf = sigmoid(hcal[b, s, :] . Wc2[s] + bc2[s])
    conf_kernel<<<NB / 4, 256, 0, stream>>>(hcal, style_idx, Wc2, bc2, conf_out);
}

// Round 3
// 567.926 us; speedup vs baseline: 1.2305x; 1.2305x over previous
//
#include <hip/hip_runtime.h>
#include <hip/hip_bf16.h>
#include <stdint.h>

typedef __hip_bfloat16 bf16;
typedef __attribute__((ext_vector_type(8))) short short8;
typedef __attribute__((ext_vector_type(4))) float f32x4;

#define NB 32768
#define NC 1024
#define NH 1024
#define NS 8
#define NDC 64

__device__ __forceinline__ void gload_lds16(const void* g, void* l) {
    __builtin_amdgcn_global_load_lds((const __attribute__((address_space(1))) void*)g,
                                     (__attribute__((address_space(3))) void*)l, 16, 0, 0);
}

__device__ __forceinline__ short f2bf(float x) {
    bf16 h = __float2bfloat16(x);
    short s;
    __builtin_memcpy(&s, &h, 2);
    return s;
}

// ---------------- fp32 -> bf16 bulk convert (8 elems/thread) ----------------
__global__ __launch_bounds__(256) void convert_kernel(
    const float* __restrict__ in, bf16* __restrict__ out)
{
    const size_t i = ((size_t)blockIdx.x * 256 + threadIdx.x) * 8;
    float4 a = *(const float4*)(in + i);
    float4 b = *(const float4*)(in + i + 4);
    short8 v;
    v[0] = f2bf(a.x); v[1] = f2bf(a.y); v[2] = f2bf(a.z); v[3] = f2bf(a.w);
    v[4] = f2bf(b.x); v[5] = f2bf(b.y); v[6] = f2bf(b.z); v[7] = f2bf(b.w);
    *(short8*)((short*)out + i) = v;
}

// ---------------- batched tiled transpose + downcast: out[c][r] = bf16(in[r][c]) ----------------
__global__ __launch_bounds__(256) void transpose_kernel(
    const float* __restrict__ in, bf16* __restrict__ out,
    int R, int Ccols, long long in_bs, long long out_bs)
{
    __shared__ float tile[32][33];
    const float* inb = in + (long long)blockIdx.z * in_bs;
    bf16* outb = out + (long long)blockIdx.z * out_bs;
    int c0 = blockIdx.x * 32, r0 = blockIdx.y * 32;
    int tx = threadIdx.x, ty = threadIdx.y; // 32 x 8
#pragma unroll
    for (int i = 0; i < 32; i += 8)
        tile[ty + i][tx] = inb[(size_t)(r0 + ty + i) * Ccols + c0 + tx];
    __syncthreads();
#pragma unroll
    for (int i = 0; i < 32; i += 8)
        outb[(size_t)(c0 + ty + i) * R + r0 + tx] = __float2bfloat16(tile[tx][ty + i]);
}

// ---------------- style_contrib split-K stage 1 ----------------
// partial[ks][s][h] = sum_{k in slice ks} style_emb[s][k] * Wa1[C+k][h]
// grid: 256 blocks = 64 k-slices x 4 h-blocks, 256 threads (one h each)
__global__ __launch_bounds__(256) void style_partial_kernel(
    const float* __restrict__ style_emb, const float* __restrict__ Wa1,
    float* __restrict__ partial)
{
    const int h = (blockIdx.x & 3) * 256 + threadIdx.x;
    const int ks = blockIdx.x >> 2;
    float acc[NS];
#pragma unroll
    for (int s = 0; s < NS; ++s) acc[s] = 0.f;
#pragma unroll
    for (int kk = 0; kk < 16; ++kk) {
        const int k = ks * 16 + kk;
        const float w = Wa1[(size_t)(NC + k) * NH + h];
#pragma unroll
        for (int s = 0; s < NS; ++s)
            acc[s] += style_emb[s * NH + k] * w;   // emb is wave-uniform -> scalar loads
    }
#pragma unroll
    for (int s = 0; s < NS; ++s)
        partial[((size_t)ks * NS + s) * NH + h] = acc[s];
}

// ---------------- style_contrib split-K stage 2: out[s][h] = ba1[h] + sum_ks partial ----------------
__global__ __launch_bounds__(256) void style_reduce_kernel(
    const float* __restrict__ partial, const float* __restrict__ ba1,
    float* __restrict__ out)
{
    const int i = blockIdx.x * 256 + threadIdx.x; // 8192 = NS*NH
    const int h = i & (NH - 1);
    const int s = i >> 10;
    float acc = ba1[h];
#pragma unroll 8
    for (int ks = 0; ks < 64; ++ks)
        acc += partial[((size_t)ks * NS + s) * NH + h];
    out[i] = acc;
}

// ---------------- m97-style bf16 GEMM: C = epilogue(A(MxK) @ BT(NxK)^T) ----------------
// MODE 0: bf16 out = relu(acc + style_contrib[style_idx[row]][col])     -> hidden
// MODE 1: f32  out = acc + resid[row][col] + bias[col]                  -> adjusted_logits
// MODE 2: bf16 out = relu(acc + bias[col])                              -> h_cal
template<int MODE>
__global__ __launch_bounds__(256, 2) void gemm_kernel(
    const bf16* __restrict__ A, const bf16* __restrict__ BT,
    bf16* __restrict__ Cb, float* __restrict__ Cf,
    int N, int K,
    const float* __restrict__ style_contrib, const int* __restrict__ style_idx,
    const float* __restrict__ resid, const float* __restrict__ bias)
{
    __shared__ short lA[128 * 32];
    __shared__ short lB[128 * 32];

    const int t = threadIdx.x;
    const int lane = t & 63;
    const int wave = t >> 6;
    const int wr = wave >> 1;
    const int wc = wave & 1;
    const int bm0 = blockIdx.y * 128;
    const int bn0 = blockIdx.x * 128;

    const int r0 = t >> 2;        // staging row
    const int c8 = (t & 3) * 8;   // staging k-chunk

    const int mrow = lane & 15;
    const int quad = lane >> 4;

    f32x4 acc[4][4];
#pragma unroll
    for (int i = 0; i < 4; ++i)
#pragma unroll
        for (int j = 0; j < 4; ++j) acc[i][j] = (f32x4){0.f, 0.f, 0.f, 0.f};

    const bf16* gA = A + (size_t)(bm0 + r0) * K + c8;
    const bf16* gB = BT + (size_t)(bn0 + r0) * K + c8;

    for (int k0 = 0; k0 < K; k0 += 32) {
        // stage 128x32 bf16 A-tile and B-tile; LDS dst byte = t*16 (+4096 for rows 64..127)
        gload_lds16(gA + k0, lA + t * 8);
        gload_lds16(gA + (size_t)64 * K + k0, lA + 2048 + t * 8);
        gload_lds16(gB + k0, lB + t * 8);
        gload_lds16(gB + (size_t)64 * K + k0, lB + 2048 + t * 8);
        __syncthreads();

        short8 af[4], bfr[4];
#pragma unroll
        for (int i = 0; i < 4; ++i)
            af[i] = *(const short8*)(lA + (wr * 64 + i * 16 + mrow) * 32 + quad * 8);
#pragma unroll
        for (int j = 0; j < 4; ++j)
            bfr[j] = *(const short8*)(lB + (wc * 64 + j * 16 + mrow) * 32 + quad * 8);
#pragma unroll
        for (int i = 0; i < 4; ++i)
#pragma unroll
            for (int j = 0; j < 4; ++j)
                acc[i][j] = __builtin_amdgcn_mfma_f32_16x16x32_bf16(af[i], bfr[j], acc[i][j], 0, 0, 0);
        __syncthreads();
    }

    // epilogue: C/D layout col = lane&15, row = quad*4 + reg
#pragma unroll
    for (int i = 0; i < 4; ++i) {
#pragma unroll
        for (int r = 0; r < 4; ++r) {
            const int grow = bm0 + wr * 64 + i * 16 + quad * 4 + r;
            const float* scrow = nullptr;
            const float* resrow = nullptr;
            if (MODE == 0) scrow = style_contrib + (size_t)style_idx[grow] * N;
            if (MODE == 1) resrow = resid + (size_t)grow * N;
#pragma unroll
            for (int j = 0; j < 4; ++j) {
                const int gcol = bn0 + wc * 64 + j * 16 + mrow;
                float v = acc[i][j][r];
                if (MODE == 0) {
                    v += scrow[gcol];
                    v = fmaxf(v, 0.f);
                    Cb[(size_t)grow * N + gcol] = __float2bfloat16(v);
                } else if (MODE == 1) {
                    v += resrow[gcol] + bias[gcol];
                    Cf[(size_t)grow * N + gcol] = v;
                } else {
                    v += bias[gcol];
                    v = fmaxf(v, 0.f);
                    Cb[(size_t)grow * N + gcol] = __float2bfloat16(v);
                }
            }
        }
    }
}

// ---------------- row softmax (1024 cols), f32 in -> bf16 out ----------------
__global__ __launch_bounds__(256) void softmax_kernel(
    const float* __restrict__ in, bf16* __restrict__ out)
{
    const size_t row = blockIdx.x;
    const float* x = in + row * NC;
    bf16* o = out + row * NC;
    const int t = threadIdx.x;
    __shared__ float red[8];

    float v[4];
    float m = -1e30f;
#pragma unroll
    for (int i = 0; i < 4; ++i) {
        v[i] = x[t + i * 256];
        m = fmaxf(m, v[i]);
    }
#pragma unroll
    for (int off = 1; off < 64; off <<= 1) m = fmaxf(m, __shfl_xor(m, off, 64));
    const int wv = t >> 6;
    if ((t & 63) == 0) red[wv] = m;
    __syncthreads();
    const float gm = fmaxf(fmaxf(red[0], red[1]), fmaxf(red[2], red[3]));

    float s = 0.f;
#pragma unroll
    for (int i = 0; i < 4; ++i) {
        v[i] = __expf(v[i] - gm);
        s += v[i];
    }
#pragma unroll
    for (int off = 1; off < 64; off <<= 1) s += __shfl_xor(s, off, 64);
    if ((t & 63) == 0) red[4 + wv] = s;
    __syncthreads();
    const float inv = 1.0f / (red[4] + red[5] + red[6] + red[7]);
#pragma unroll
    for (int i = 0; i < 4; ++i) o[t + i * 256] = __float2bfloat16(v[i] * inv);
}

// ---------------- confidence: select style, 64-dot, sigmoid ----------------
__global__ __launch_bounds__(256) void conf_kernel(
    const bf16* __restrict__ hcal, const int* __restrict__ style_idx,
    const float* __restrict__ Wc2, const float* __restrict__ bc2,
    float* __restrict__ out)
{
    const int t = threadIdx.x;
    const int lane = t & 63;
    const int b = blockIdx.x * 4 + (t >> 6);
    const int s = style_idx[b];
    float p = __bfloat162float(hcal[(size_t)b * (NS * NDC) + s * NDC + lane]) *
              Wc2[s * NDC + lane];
#pragma unroll
    for (int off = 1; off < 64; off <<= 1) p += __shfl_xor(p, off, 64);
    if (lane == 0) {
        float z = p + bc2[s];
        out[b] = 1.0f / (1.0f + __expf(-z));
    }
}

extern "C" void kernel_launch(void* const* d_in, const int* in_sizes, int n_in,
                              void* d_out, int out_size, void* d_ws, size_t ws_size,
                              hipStream_t stream) {
    const float* logits    = (const float*)d_in[0];
    const int*   style_idx = (const int*)d_in[1];
    const float* style_emb = (const float*)d_in[2];
    const float* Wa1       = (const float*)d_in[3];
    const float* ba1       = (const float*)d_in[4];
    const float* Wa2       = (const float*)d_in[5];
    const float* ba2       = (const float*)d_in[6];
    const float* Wc1       = (const float*)d_in[7];
    const float* bc1       = (const float*)d_in[8];
    const float* Wc2       = (const float*)d_in[9];
    const float* bc2       = (const float*)d_in[10];

    char* ws = (char*)d_ws;
    bf16* logits_b = (bf16*)ws;        ws += (size_t)NB * NC * 2;          // 64 MB
    bf16* hidden = (bf16*)ws;          ws += (size_t)NB * NH * 2;          // 64 MB (reused as probs)
    bf16* W1T = (bf16*)ws;             ws += (size_t)NC * NH * 2;          // 2 MB
    bf16* W2T = (bf16*)ws;             ws += (size_t)NH * NC * 2;          // 2 MB
    bf16* Wc1T = (bf16*)ws;            ws += (size_t)NS * NDC * NC * 2;    // 1 MB
    float* style_contrib = (float*)ws; ws += (size_t)NS * NH * 4;          // 32 KB
    float* style_partial = (float*)ws; ws += (size_t)64 * NS * NH * 4;     // 2 MB
    // hcal aliases logits_b: logits_b is dead after gemm<0> (gemm<1> uses fp32 logits residual)
    bf16* hcal = logits_b;                                                 // 32 MB

    float* adjusted = (float*)d_out;
    float* conf_out = (float*)d_out + (size_t)NB * NC;

    // logits -> bf16
    convert_kernel<<<(NB * NC) / (256 * 8), 256, 0, stream>>>(logits, logits_b);

    dim3 tb(32, 8);
    // W1T[n][k] = Wa1[k][n] (first C rows of Wa1)
    transpose_kernel<<<dim3(32, 32, 1), tb, 0, stream>>>(Wa1, W1T, NC, NH, 0, 0);
    // W2T[n][k] = Wa2[k][n]
    transpose_kernel<<<dim3(32, 32, 1), tb, 0, stream>>>(Wa2, W2T, NH, NC, 0, 0);
    // Wc1T[s*64+d][c] = Wc1[s][c][d]  (batched 1024x64 -> 64x1024 per style)
    transpose_kernel<<<dim3(2, 32, NS), tb, 0, stream>>>(Wc1, Wc1T, NC, NDC,
                                                         (long long)NC * NDC, (long long)NDC * NC);
    // style_contrib = ba1 + style_emb @ Wa1[C:]  (split-K: 64 slices, then reduce)
    style_partial_kernel<<<256, 256, 0, stream>>>(style_emb, Wa1, style_partial);
    style_reduce_kernel<<<NS * NH / 256, 256, 0, stream>>>(style_partial, ba1, style_contrib);

    // hidden = relu(logits @ Wa1[:C] + style_contrib[style])
    gemm_kernel<0><<<dim3(NH / 128, NB / 128), 256, 0, stream>>>(
        logits_b, W1T, hidden, nullptr, NH, NC, style_contrib, style_idx, nullptr, nullptr);
    // adjusted = logits + hidden @ Wa2 + ba2   (f32 out, f32 residual)
    gemm_kernel<1><<<dim3(NC / 128, NB / 128), 256, 0, stream>>>(
        hidden, W2T, nullptr, adjusted, NC, NH, nullptr, nullptr, logits, ba2);
    // probs = softmax(adjusted)  (reuse hidden buffer)
    softmax_kernel<<<NB, 256, 0, stream>>>(adjusted, hidden);
    // hcal = relu(probs @ Wc1 + bc1), all styles dense (N = S*DC = 512)
    gemm_kernel<2><<<dim3((NS * NDC) / 128, NB / 128), 256, 0, stream>>>(
        hidden, Wc1T, hcal, nullptr, NS * NDC, NC, nullptr, nullptr, nullptr, bc1);
    // conf = sigmoid(hcal[b, s, :] . Wc2[s] + bc2[s])
    conf_kernel<<<NB / 4, 256, 0, stream>>>(hcal, style_idx, Wc2, bc2, conf_out);
}